// Round 12
// baseline (3626.085 us; speedup 1.0000x reference)
//
#include <hip/hip_runtime.h>
#include <hip/hip_bf16.h>
#include <math.h>

// Problem constants
constexpr int NB  = 32;      // batch
constexpr int NS  = 256;     // seq len
constexpr int NE  = 1024;    // embed dim
constexpr int NH  = 1024;    // LSTM output dim (2*NHD)
constexpr int NHD = 512;     // per-direction hidden
constexpr int NG  = 2048;    // 4*NHD gates
constexpr int NP  = 16;      // prompt positions
constexpr int NBS = NB * NS; // 8192 rows
constexpr int GK  = 1024;    // GEMM K (= NE = NH)

// Persistent LSTM decomposition: UPW=16 units/WG, 32 WGs/dir, 64 total
constexpr int UPW  = 16;
constexpr int NWGD = NHD / UPW;  // 32 WGs per direction
// Gt layout: [d][slice 32][t 256][b 32][uloc 16][gate 4] fp32
constexpr size_t GT_DIR = (size_t)NWGD * 256 * 2048;   // 16.7M elems/dir

typedef __attribute__((ext_vector_type(8))) short bf16x8;
typedef __attribute__((ext_vector_type(4))) float f32x4;
typedef unsigned short u16;
typedef unsigned long long u64;

__device__ __forceinline__ float sigm(float x) {
    return __fdividef(1.0f, 1.0f + __expf(-x));
}
__device__ __forceinline__ float tanhfast(float x) {
    float t = __expf(2.0f * x);
    return 1.0f - __fdividef(2.0f, t + 1.0f);
}
__device__ __forceinline__ u16 f2bf(float f) {
    union { float f; unsigned u; } v; v.f = f;
    unsigned r = v.u + 0x7FFF + ((v.u >> 16) & 1);   // RNE
    return (u16)(r >> 16);
}
__device__ __forceinline__ float bf2f(u16 b) {
    return __uint_as_float((unsigned)b << 16);
}

// ---------------------------------------------------------------------------
__global__ void k_zero(int* p) { p[blockIdx.x * 256 + threadIdx.x] = 0; }

// ---------------------------------------------------------------------------
// allb_bf[s][b][1024] (bf16) = emb[id]+ctx[id], prompt_emb at prompt slots
// ---------------------------------------------------------------------------
__global__ void k_allb(const float* __restrict__ emb, const float* __restrict__ ctx,
                       const float* __restrict__ pemb, const int* __restrict__ ids,
                       const int* __restrict__ pidx, u16* __restrict__ allb) {
    int r = blockIdx.x;            // r = b*NS + s
    int b = r >> 8, s = r & 255;
    __shared__ int ppos;
    if (threadIdx.x == 0) {
        int t = -1;
        #pragma unroll
        for (int p = 0; p < NP; ++p)
            if (pidx[b * NP + p] == s) t = p;
        ppos = t;
    }
    __syncthreads();
    int e = threadIdx.x;
    float4 v;
    if (ppos >= 0) {
        v = ((const float4*)(pemb + (size_t)ppos * NE))[e];
    } else {
        int id = ids[r];
        float4 a = ((const float4*)(emb + (size_t)id * NE))[e];
        float4 c = ((const float4*)(ctx + (size_t)id * NE))[e];
        v = make_float4(a.x + c.x, a.y + c.y, a.z + c.z, a.w + c.w);
    }
    ushort4 o;
    o.x = f2bf(v.x); o.y = f2bf(v.y); o.z = f2bf(v.z); o.w = f2bf(v.w);
    *(ushort4*)(allb + ((size_t)(s * NB + b)) * NE + e * 4) = o;
}

// ---------------------------------------------------------------------------
__global__ void k_raw(const float* __restrict__ emb, const int* __restrict__ ids,
                      float* __restrict__ out) {
    int r = blockIdx.x;
    int id = ids[r];
    ((float4*)(out + (size_t)r * NE))[threadIdx.x] =
        ((const float4*)(emb + (size_t)id * NE))[threadIdx.x];
}

// ---------------------------------------------------------------------------
// Wih ([2][2048][1024] fp32, gate-major rows) -> Wbf (bf16, UNIT-MAJOR rows:
// n' = unit*4+gate) + combined bias in same order.
// ---------------------------------------------------------------------------
__global__ void k_wcvt(const float* __restrict__ Wih, const float* __restrict__ bih,
                       const float* __restrict__ bhh, u16* __restrict__ Wbf,
                       float* __restrict__ biasC) {
    int blk = blockIdx.x;               // [2][2048]
    int d = blk >> 11, np = blk & 2047;
    int rw = (np & 3) * 512 + (np >> 2);
    const float* src = Wih + ((size_t)d * NG + rw) * GK;
    u16* dst = Wbf + ((size_t)d * NG + np) * GK;
    int t = threadIdx.x;
    float4 v = ((const float4*)src)[t];
    ushort4 o;
    o.x = f2bf(v.x); o.y = f2bf(v.y); o.z = f2bf(v.z); o.w = f2bf(v.w);
    ((ushort4*)dst)[t] = o;
    if (t == 0)
        biasC[d * NG + np] = bih[d * NG + rw] + bhh[d * NG + rw];
}

// ---------------------------------------------------------------------------
// bf16 MFMA GEMM: Gt = A[m',k] @ Wbf[n',k]^T + biasC  (proven R5 structure)
// ---------------------------------------------------------------------------
__global__ __launch_bounds__(256) void k_gemm_m(const u16* __restrict__ A0,
                                                const u16* __restrict__ A1,
                                                int astride,
                                                const u16* __restrict__ W,
                                                const float* __restrict__ bc,
                                                float* __restrict__ Gt) {
    __shared__ char At[128 * 128];
    __shared__ char Wt[128 * 128];
    int tid = threadIdx.x;
    int lane = tid & 63, w = tid >> 6;
    int n0 = blockIdx.x * 128, m0 = blockIdx.y * 128;
    int r = tid >> 1, h = tid & 1;      // staging: row r, half h

    f32x4 acc[4][4];
    #pragma unroll
    for (int i = 0; i < 4; ++i)
        #pragma unroll
        for (int j = 0; j < 4; ++j) acc[i][j] = (f32x4){0.f, 0.f, 0.f, 0.f};

    unsigned rsw = (unsigned)((r & 7) << 4);
    for (int kt = 0; kt < GK; kt += 64) {
        {
            int k0 = kt + h * 32;
            const u16* asrc = (k0 < 512) ? (A0 + (size_t)(m0 + r) * astride + k0)
                                         : (A1 + (size_t)(m0 + r) * astride + (k0 - 512));
            const u16* wsrc = W + (size_t)(n0 + r) * GK + k0;
            #pragma unroll
            for (int j = 0; j < 4; ++j) {
                uint4 va = *(const uint4*)(asrc + j * 8);
                *(uint4*)(At + r * 128 + (((unsigned)(h * 64 + j * 16)) ^ rsw)) = va;
                uint4 vw = *(const uint4*)(wsrc + j * 8);
                *(uint4*)(Wt + r * 128 + (((unsigned)(h * 64 + j * 16)) ^ rsw)) = vw;
            }
        }
        __syncthreads();
        #pragma unroll
        for (int sub = 0; sub < 2; ++sub) {
            bf16x8 af[4], bfr[4];
            int kbyte = sub * 64 + (lane >> 4) * 16;
            #pragma unroll
            for (int ni = 0; ni < 4; ++ni) {
                int rr = (w & 1) * 64 + ni * 16 + (lane & 15);
                af[ni] = *(const bf16x8*)(Wt + rr * 128 + ((unsigned)kbyte ^ ((unsigned)((rr & 7) << 4))));
            }
            #pragma unroll
            for (int mi = 0; mi < 4; ++mi) {
                int rr = (w >> 1) * 64 + mi * 16 + (lane & 15);
                bfr[mi] = *(const bf16x8*)(At + rr * 128 + ((unsigned)kbyte ^ ((unsigned)((rr & 7) << 4))));
            }
            #pragma unroll
            for (int mi = 0; mi < 4; ++mi)
                #pragma unroll
                for (int ni = 0; ni < 4; ++ni)
                    acc[mi][ni] = __builtin_amdgcn_mfma_f32_16x16x32_bf16(
                        af[ni], bfr[mi], acc[mi][ni], 0, 0, 0);
        }
        __syncthreads();
    }
    // epilogue: float4 (4 gates of one unit) -> Gt[slice][t][b][uloc][g]
    #pragma unroll
    for (int mi = 0; mi < 4; ++mi) {
        int mp = m0 + (w >> 1) * 64 + mi * 16 + (lane & 15);
        int t = mp >> 5, b = mp & 31;
        #pragma unroll
        for (int ni = 0; ni < 4; ++ni) {
            int npb = n0 + (w & 1) * 64 + ni * 16 + (lane >> 4) * 4;
            int unit = npb >> 2;
            float4 bv = *(const float4*)(bc + npb);
            f32x4 a = acc[mi][ni];
            float4 o = make_float4(a[0] + bv.x, a[1] + bv.y, a[2] + bv.z, a[3] + bv.w);
            *(float4*)(Gt + ((size_t)((unit >> 4) * NS + t)) * 2048 + b * 64 + (unit & 15) * 4) = o;
        }
    }
}

// ---------------------------------------------------------------------------
// Wave-autonomous persistent MFMA LSTM (R9 exchange, leaner rendezvous).
// Grid = 64 WGs: wg&1 = dir, wg>>1 = slice (16 units); wave w owns units
// 4w..4w+3 (x4 gates), wfrag[16] resident. Changes vs R9:
//  - per-WAVE publish: each wave drains its own vmcnt(0) and publishes its
//    own 64B line (128 lines/dir) - no WG-wide pre-publish syncthreads.
//  - coalesced h stores: 8 __shfl gather the wave's 4-unit x 32-batch block
//    in-register; lanes 0-31 issue ONE u64 sc1 store each (128/WG vs 512).
//  - single __syncthreads per step (staging-write -> MFMA-read) with LDS
//    ping-pong tiles (2 x 32KB).
// Consumer side unchanged: poll lines (all lanes, 2 each) then plain cached
// staging loads (first-touch per step -> coherent; L2-shared).
// Uniform control flow; publish precedes poll each step; monotonic lines
// zeroed per launch -> same inductive no-deadlock argument as R9.
// ---------------------------------------------------------------------------
__global__ __launch_bounds__(256) void k_lstm_w(const float* __restrict__ Gt,
                                                const float* __restrict__ Whh,
                                                u16* __restrict__ hxb,
                                                int* __restrict__ cblk) {
    __shared__ char hlds[2][NB * NHD * 2];   // ping-pong 32 KB bf16 tiles
    int wg = blockIdx.x;
    int d = wg & 1;
    int slice = wg >> 1;            // 0..31
    int n0 = slice * UPW;
    int tid = threadIdx.x;
    int lane = tid & 63;
    int w = tid >> 6;               // wave 0..3
    int* lines  = cblk + d * 2048;         // 128 lines x 16 ints (64B apart)
    int* myline = lines + (slice * 4 + w) * 16;
    int pidx0 = lane * 16;                 // poll lines: lane, lane+64
    int pidx1 = (lane + 64) * 16;
    u16* hxd = hxb + (size_t)d * NS * NB * NHD;
    const float* Gd = Gt + (size_t)d * GT_DIR + (size_t)slice * NS * 2048;

    // resident A fragments (Whh fp32 -> bf16); per-wave-unique rows
    bf16x8 wfrag[16];
    {
        int rloc = lane & 15;
        int usub = rloc >> 2, g = rloc & 3;
        int kb0 = lane >> 4;
        const float* wrow = Whh + ((size_t)d * NG + g * NHD + n0 + 4 * w + usub) * NHD;
        #pragma unroll
        for (int kk = 0; kk < 16; ++kk) {
            const float* p = wrow + kk * 32 + kb0 * 8;
            float4 x = *(const float4*)p;
            float4 y = *(const float4*)(p + 4);
            bf16x8 wf;
            wf[0] = (short)f2bf(x.x); wf[1] = (short)f2bf(x.y);
            wf[2] = (short)f2bf(x.z); wf[3] = (short)f2bf(x.w);
            wf[4] = (short)f2bf(y.x); wf[5] = (short)f2bf(y.y);
            wf[6] = (short)f2bf(y.z); wf[7] = (short)f2bf(y.w);
            wfrag[kk] = wf;
        }
    }
    int uloc  = 4 * w + (lane >> 4);       // unit within slice (C layout)
    int unitC = n0 + uloc;                 // global unit
    (void)unitC;
    int bcol0 = lane & 15;                 // batch, tile 0
    int bcol1 = 16 + bcol0;                // batch, tile 1
    int kb    = lane >> 4;                 // B-fragment k-block
    // per-wave staging role: rows 8w..8w+7, 128B chunk c8
    int sRow = 8 * w + (lane >> 3);
    int c8   = lane & 7;
    unsigned rsw = (unsigned)((sRow & 7) << 4);
    unsigned s0 = (unsigned)((bcol0 & 7) << 4);
    unsigned s1 = (unsigned)((bcol1 & 7) << 4);

    float c0 = 0.f, c1 = 0.f;
    uint4 st[8];                           // staged h chunk (128B/thread)
    // prologue: G prefetch for step 0
    int ttp = d ? (NS - 1) : 0;
    float4 Gv0 = *(const float4*)(Gd + (size_t)ttp * 2048 + bcol0 * 64 + uloc * 4);
    float4 Gv1 = *(const float4*)(Gd + (size_t)ttp * 2048 + bcol1 * 64 + uloc * 4);

    for (int step = 0; step < NS; ++step) {
        int tt = d ? (NS - 1 - step) : step;
        f32x4 acc0 = {0.f, 0.f, 0.f, 0.f};
        f32x4 acc1 = {0.f, 0.f, 0.f, 0.f};
        if (step) {
            char* tile = hlds[step & 1];
            // write this wave's staged rows -> ping-pong tile (compiler
            // inserts the vmcnt wait on st regs loaded last iteration)
            char* dstrow = tile + sRow * 1024;
            #pragma unroll
            for (int i = 0; i < 8; ++i)
                *(uint4*)(dstrow + (((unsigned)(c8 * 128 + i * 16)) ^ rsw)) = st[i];
            __syncthreads();               // tile complete for all waves
            const char* b0base = tile + bcol0 * 1024;
            const char* b1base = tile + bcol1 * 1024;
            #pragma unroll
            for (int kk = 0; kk < 16; ++kk) {
                bf16x8 b0 = *(const bf16x8*)(b0base + (((unsigned)(kk * 64 + kb * 16)) ^ s0));
                bf16x8 b1 = *(const bf16x8*)(b1base + (((unsigned)(kk * 64 + kb * 16)) ^ s1));
                acc0 = __builtin_amdgcn_mfma_f32_16x16x32_bf16(wfrag[kk], b0, acc0, 0, 0, 0);
                acc1 = __builtin_amdgcn_mfma_f32_16x16x32_bf16(wfrag[kk], b1, acc1, 0, 0, 0);
            }
        }
        // gates (reg q = gate q: i,f,g,o) -> bf16 h values in u32
        unsigned v0, v1;
        {
            float ig = sigm(acc0[0] + Gv0.x);
            float fg = sigm(acc0[1] + Gv0.y);
            float gg = tanhfast(acc0[2] + Gv0.z);
            float og = sigm(acc0[3] + Gv0.w);
            c0 = fg * c0 + ig * gg;
            v0 = (unsigned)f2bf(og * tanhfast(c0));
        }
        {
            float ig = sigm(acc1[0] + Gv1.x);
            float fg = sigm(acc1[1] + Gv1.y);
            float gg = tanhfast(acc1[2] + Gv1.z);
            float og = sigm(acc1[3] + Gv1.w);
            c1 = fg * c1 + ig * gg;
            v1 = (unsigned)f2bf(og * tanhfast(c1));
        }
        // in-register transpose: store-lane s holds u64 = h(units 4w..4w+3,
        // batch s). s<16 from v0 (batches 0-15), s in 16..31 from v1.
        {
            int bl = lane & 15;
            unsigned a0 = __shfl(v0, bl);
            unsigned a1 = __shfl(v0, bl + 16);
            unsigned a2 = __shfl(v0, bl + 32);
            unsigned a3 = __shfl(v0, bl + 48);
            unsigned b0 = __shfl(v1, bl);
            unsigned b1 = __shfl(v1, bl + 16);
            unsigned b2 = __shfl(v1, bl + 32);
            unsigned b3 = __shfl(v1, bl + 48);
            bool lo = (lane < 16);
            unsigned k0 = lo ? a0 : b0, k1 = lo ? a1 : b1;
            unsigned k2 = lo ? a2 : b2, k3 = lo ? a3 : b3;
            u64 val = (u64)(k0 | (k1 << 16)) | ((u64)(k2 | (k3 << 16)) << 32);
            if (lane < 32)
                __hip_atomic_store((u64*)(hxd + ((size_t)tt * NB + lane) * NHD + n0 + 4 * w),
                                   val, __ATOMIC_RELAXED, __HIP_MEMORY_SCOPE_AGENT);
        }
        if (step == NS - 1) break;         // last step: no exchange needed
        // per-wave: own stores drained, publish own line
        asm volatile("s_waitcnt vmcnt(0)" ::: "memory");
        if (lane == 0)
            __hip_atomic_store(myline, step + 1, __ATOMIC_RELAXED,
                               __HIP_MEMORY_SCOPE_AGENT);
        // G prefetch for t+1 (issues before poll; hides under it)
        {
            int ttn = d ? tt - 1 : tt + 1;
            Gv0 = *(const float4*)(Gd + (size_t)ttn * 2048 + bcol0 * 64 + uloc * 4);
            Gv1 = *(const float4*)(Gd + (size_t)ttn * 2048 + bcol1 * 64 + uloc * 4);
        }
        asm volatile("" ::: "memory");     // pin prefetch issue before poll
        // poll all 128 lines of this direction (each lane: 2 lines)
        {
            int target = step + 1;
            for (;;) {
                int a = __hip_atomic_load(lines + pidx0, __ATOMIC_RELAXED,
                                          __HIP_MEMORY_SCOPE_AGENT);
                int b = __hip_atomic_load(lines + pidx1, __ATOMIC_RELAXED,
                                          __HIP_MEMORY_SCOPE_AGENT);
                if (__all(a >= target && b >= target)) break;
                __builtin_amdgcn_s_sleep(1);
            }
        }
        asm volatile("" ::: "memory");     // pin staging loads after poll
        // issue staging loads of h(tt) (plain cached; consumed next iter)
        {
            const u16* srow = hxd + ((size_t)tt * NB + sRow) * NHD + c8 * 64;
            #pragma unroll
            for (int i = 0; i < 8; ++i) st[i] = *(const uint4*)(srow + i * 8);
        }
    }
}

// ---------------------------------------------------------------------------
// MLP stage 1: mid[512][1024] = relu(hrow @ W1^T + b1), rows from hx_bf
// ---------------------------------------------------------------------------
__global__ __launch_bounds__(256) void k_mlp1(const u16* __restrict__ hxb,
                                              const int* __restrict__ pidx,
                                              const float* __restrict__ W1,
                                              const float* __restrict__ b1,
                                              float* __restrict__ mid) {
    __shared__ float As[16][65];
    __shared__ float Ws[16][65];
    int tid = threadIdx.x;
    int tx = tid & 15, ty = tid >> 4;
    int n0 = blockIdx.x * 64, m0 = blockIdx.y * 64;
    int lr = tid >> 2;
    int lk = (tid & 3) * 4;
    int m = m0 + lr;
    int bb = m >> 4;
    int s = pidx[m];
    float acc[4][4] = {};
    for (int kt = 0; kt < GK; kt += 16) {
        int k0 = kt + lk;
        int half = k0 >> 9;
        ushort4 av4 = *(const ushort4*)(hxb + (((size_t)(half * NS + s)) * NB + bb) * NHD + (k0 & 511));
        float4 wv = *(const float4*)(W1 + (size_t)(n0 + lr) * GK + k0);
        As[lk + 0][lr] = bf2f(av4.x); As[lk + 1][lr] = bf2f(av4.y);
        As[lk + 2][lr] = bf2f(av4.z); As[lk + 3][lr] = bf2f(av4.w);
        Ws[lk + 0][lr] = wv.x; Ws[lk + 1][lr] = wv.y;
        Ws[lk + 2][lr] = wv.z; Ws[lk + 3][lr] = wv.w;
        __syncthreads();
        #pragma unroll
        for (int kk = 0; kk < 16; ++kk) {
            float a[4], wv2[4];
            #pragma unroll
            for (int i = 0; i < 4; ++i) a[i] = As[kk][ty * 4 + i];
            #pragma unroll
            for (int j = 0; j < 4; ++j) wv2[j] = Ws[kk][tx * 4 + j];
            #pragma unroll
            for (int i = 0; i < 4; ++i)
                #pragma unroll
                for (int j = 0; j < 4; ++j) acc[i][j] += a[i] * wv2[j];
        }
        __syncthreads();
    }
    #pragma unroll
    for (int j = 0; j < 4; ++j) {
        int n = n0 + tx * 4 + j;
        float bias = b1[n];
        #pragma unroll
        for (int i = 0; i < 4; ++i)
            mid[(size_t)(m0 + ty * 4 + i) * 1024 + n] = fmaxf(acc[i][j] + bias, 0.f);
    }
}

// ---------------------------------------------------------------------------
// MLP stage 2: out[b, s] = mid @ W2^T + b2 + pemb[p], scattered to d_out.
// ---------------------------------------------------------------------------
__global__ __launch_bounds__(256) void k_mlp2(const float* __restrict__ mid,
                                              const int* __restrict__ pidx,
                                              const float* __restrict__ W2,
                                              const float* __restrict__ b2,
                                              const float* __restrict__ pemb,
                                              float* __restrict__ out) {
    __shared__ float As[16][65];
    __shared__ float Ws[16][65];
    int tid = threadIdx.x;
    int tx = tid & 15, ty = tid >> 4;
    int n0 = blockIdx.x * 64, m0 = blockIdx.y * 64;
    int lr = tid >> 2;
    int lk = (tid & 3) * 4;
    float acc[4][4] = {};
    for (int kt = 0; kt < GK; kt += 16) {
        float4 av = *(const float4*)(mid + (size_t)(m0 + lr) * GK + kt + lk);
        float4 wv = *(const float4*)(W2 + (size_t)(n0 + lr) * GK + kt + lk);
        As[lk + 0][lr] = av.x; As[lk + 1][lr] = av.y;
        As[lk + 2][lr] = av.z; As[lk + 3][lr] = av.w;
        Ws[lk + 0][lr] = wv.x; Ws[lk + 1][lr] = wv.y;
        Ws[lk + 2][lr] = wv.z; Ws[lk + 3][lr] = wv.w;
        __syncthreads();
        #pragma unroll
        for (int kk = 0; kk < 16; ++kk) {
            float a[4], wv2[4];
            #pragma unroll
            for (int i = 0; i < 4; ++i) a[i] = As[kk][ty * 4 + i];
            #pragma unroll
            for (int j = 0; j < 4; ++j) wv2[j] = Ws[kk][tx * 4 + j];
            #pragma unroll
            for (int i = 0; i < 4; ++i)
                #pragma unroll
                for (int j = 0; j < 4; ++j) acc[i][j] += a[i] * wv2[j];
        }
        __syncthreads();
    }
    #pragma unroll
    for (int i = 0; i < 4; ++i) {
        int m = m0 + ty * 4 + i;
        int bb = m >> 4, p = m & 15;
        int s = pidx[m];
        float* orow = out + ((size_t)(bb * NS + s)) * NE;
        const float* prow = pemb + (size_t)p * NE;
        #pragma unroll
        for (int j = 0; j < 4; ++j) {
            int n = n0 + tx * 4 + j;
            orow[n] = acc[i][j] + b2[n] + prow[n];
        }
    }
}

// ---------------------------------------------------------------------------
extern "C" void kernel_launch(void* const* d_in, const int* in_sizes, int n_in,
                              void* d_out, int out_size, void* d_ws, size_t ws_size,
                              hipStream_t stream) {
    const float* emb  = (const float*)d_in[0];
    const float* ctx  = (const float*)d_in[1];
    const float* pemb = (const float*)d_in[2];
    const float* Wih0 = (const float*)d_in[3];
    const float* Whh0 = (const float*)d_in[4];
    const float* bih0 = (const float*)d_in[5];
    const float* bhh0 = (const float*)d_in[6];
    const float* Wih1 = (const float*)d_in[7];
    const float* Whh1 = (const float*)d_in[8];
    const float* bih1 = (const float*)d_in[9];
    const float* bhh1 = (const float*)d_in[10];
    const float* W1   = (const float*)d_in[11];
    const float* b1   = (const float*)d_in[12];
    const float* W2   = (const float*)d_in[13];
    const float* b2   = (const float*)d_in[14];
    const int* ids    = (const int*)d_in[15];
    const int* pidx   = (const int*)d_in[16];
    float* out = (float*)d_out;

    // Workspace layout (bytes):
    //   Gt:    [2][32][256][2048] f32 = 134217728
    //   allb:  [256][32][1024] bf16   =  16777216
    //   hx_bf: [2][256][32][512] bf16 =  16777216
    //   Wbf:   [2][2048][1024] bf16   =   8388608
    //   biasC: [2][2048] f32          =     16384
    //   mid:   [512][1024] f32        =   2097152
    //   ctr:   8192 ints (2 layers x 2 dirs x 128 lines x 16 ints)
    char* ws = (char*)d_ws;
    float* Gt    = (float*)ws;
    u16*   allb  = (u16*)(ws + 134217728u);
    u16*   hx    = (u16*)(ws + 150994944u);
    u16*   Wbf   = (u16*)(ws + 167772160u);
    float* biasC = (float*)(ws + 176160768u);
    float* mid   = (float*)(ws + 176177152u);
    int*   ctr   = (int*)(ws + 178274304u);

    k_zero<<<dim3(32), dim3(256), 0, stream>>>(ctr);
    k_allb<<<dim3(NBS), dim3(256), 0, stream>>>(emb, ctx, pemb, ids, pidx, allb);

    // Layer 0
    k_wcvt<<<dim3(2 * NG), dim3(256), 0, stream>>>(Wih0, bih0, bhh0, Wbf, biasC);
    for (int d = 0; d < 2; ++d)
        k_gemm_m<<<dim3(NG / 128, NBS / 128), dim3(256), 0, stream>>>(
            allb, allb + 512, 1024, Wbf + (size_t)d * NG * GK, biasC + d * NG,
            Gt + (size_t)d * GT_DIR);
    k_lstm_w<<<dim3(2 * NWGD), dim3(256), 0, stream>>>(Gt, Whh0, hx, ctr);

    k_raw<<<dim3(NBS), dim3(256), 0, stream>>>(emb, ids, out);

    // Layer 1 (A = hx_bf, dir halves)
    k_wcvt<<<dim3(2 * NG), dim3(256), 0, stream>>>(Wih1, bih1, bhh1, Wbf, biasC);
    for (int d = 0; d < 2; ++d)
        k_gemm_m<<<dim3(NG / 128, NBS / 128), dim3(256), 0, stream>>>(
            hx, hx + (size_t)NS * NB * NHD, 512, Wbf + (size_t)d * NG * GK,
            biasC + d * NG, Gt + (size_t)d * GT_DIR);
    k_lstm_w<<<dim3(2 * NWGD), dim3(256), 0, stream>>>(Gt, Whh1, hx, ctr + 4096);

    // MLP head at prompt rows
    k_mlp1<<<dim3(16, 8), dim3(256), 0, stream>>>(hx, pidx, W1, b1, mid);
    k_mlp2<<<dim3(16, 8), dim3(256), 0, stream>>>(mid, pidx, W2, b2, pemb, out);
}

// Round 13
// 2409.378 us; speedup vs baseline: 1.5050x; 1.5050x over previous
//
#include <hip/hip_runtime.h>
#include <hip/hip_bf16.h>
#include <math.h>

// Problem constants
constexpr int NB  = 32;      // batch
constexpr int NS  = 256;     // seq len
constexpr int NE  = 1024;    // embed dim
constexpr int NH  = 1024;    // LSTM output dim (2*NHD)
constexpr int NHD = 512;     // per-direction hidden
constexpr int NG  = 2048;    // 4*NHD gates
constexpr int NP  = 16;      // prompt positions
constexpr int NBS = NB * NS; // 8192 rows
constexpr int GK  = 1024;    // GEMM K (= NE = NH)

// Persistent LSTM decomposition: UPW=32 units/WG, 16 WGs/dir, 32 total
constexpr int UPW  = 32;
constexpr int NWGD = NHD / UPW;  // 16 WGs per direction
// Gt layout: [d][slice 16][t 256][b 32][uloc 32][gate 4] fp32
constexpr size_t GT_DIR = (size_t)NWGD * 256 * 4096;   // 16.7M elems/dir

typedef __attribute__((ext_vector_type(8))) short bf16x8;
typedef __attribute__((ext_vector_type(4))) float f32x4;
typedef unsigned short u16;
typedef unsigned long long u64;

__device__ __forceinline__ float sigm(float x) {
    return __fdividef(1.0f, 1.0f + __expf(-x));
}
__device__ __forceinline__ float tanhfast(float x) {
    float t = __expf(2.0f * x);
    return 1.0f - __fdividef(2.0f, t + 1.0f);
}
__device__ __forceinline__ u16 f2bf(float f) {
    union { float f; unsigned u; } v; v.f = f;
    unsigned r = v.u + 0x7FFF + ((v.u >> 16) & 1);   // RNE
    return (u16)(r >> 16);
}
__device__ __forceinline__ float bf2f(u16 b) {
    return __uint_as_float((unsigned)b << 16);
}

// ---------------------------------------------------------------------------
__global__ void k_zero(int* p) { p[blockIdx.x * 256 + threadIdx.x] = 0; }

// ---------------------------------------------------------------------------
// allb_bf[s][b][1024] (bf16) = emb[id]+ctx[id], prompt_emb at prompt slots
// ---------------------------------------------------------------------------
__global__ void k_allb(const float* __restrict__ emb, const float* __restrict__ ctx,
                       const float* __restrict__ pemb, const int* __restrict__ ids,
                       const int* __restrict__ pidx, u16* __restrict__ allb) {
    int r = blockIdx.x;            // r = b*NS + s
    int b = r >> 8, s = r & 255;
    __shared__ int ppos;
    if (threadIdx.x == 0) {
        int t = -1;
        #pragma unroll
        for (int p = 0; p < NP; ++p)
            if (pidx[b * NP + p] == s) t = p;
        ppos = t;
    }
    __syncthreads();
    int e = threadIdx.x;
    float4 v;
    if (ppos >= 0) {
        v = ((const float4*)(pemb + (size_t)ppos * NE))[e];
    } else {
        int id = ids[r];
        float4 a = ((const float4*)(emb + (size_t)id * NE))[e];
        float4 c = ((const float4*)(ctx + (size_t)id * NE))[e];
        v = make_float4(a.x + c.x, a.y + c.y, a.z + c.z, a.w + c.w);
    }
    ushort4 o;
    o.x = f2bf(v.x); o.y = f2bf(v.y); o.z = f2bf(v.z); o.w = f2bf(v.w);
    *(ushort4*)(allb + ((size_t)(s * NB + b)) * NE + e * 4) = o;
}

// ---------------------------------------------------------------------------
__global__ void k_raw(const float* __restrict__ emb, const int* __restrict__ ids,
                      float* __restrict__ out) {
    int r = blockIdx.x;
    int id = ids[r];
    ((float4*)(out + (size_t)r * NE))[threadIdx.x] =
        ((const float4*)(emb + (size_t)id * NE))[threadIdx.x];
}

// ---------------------------------------------------------------------------
// Wih ([2][2048][1024] fp32, gate-major rows) -> Wbf (bf16, UNIT-MAJOR rows:
// n' = unit*4+gate) + combined bias in same order.
// ---------------------------------------------------------------------------
__global__ void k_wcvt(const float* __restrict__ Wih, const float* __restrict__ bih,
                       const float* __restrict__ bhh, u16* __restrict__ Wbf,
                       float* __restrict__ biasC) {
    int blk = blockIdx.x;               // [2][2048]
    int d = blk >> 11, np = blk & 2047;
    int rw = (np & 3) * 512 + (np >> 2);
    const float* src = Wih + ((size_t)d * NG + rw) * GK;
    u16* dst = Wbf + ((size_t)d * NG + np) * GK;
    int t = threadIdx.x;
    float4 v = ((const float4*)src)[t];
    ushort4 o;
    o.x = f2bf(v.x); o.y = f2bf(v.y); o.z = f2bf(v.z); o.w = f2bf(v.w);
    ((ushort4*)dst)[t] = o;
    if (t == 0)
        biasC[d * NG + np] = bih[d * NG + rw] + bhh[d * NG + rw];
}

// ---------------------------------------------------------------------------
// bf16 MFMA GEMM: Gt = A[m',k] @ Wbf[n',k]^T + biasC  (proven R5 structure;
// epilogue retargeted to the UPW=32 Gt layout)
// ---------------------------------------------------------------------------
__global__ __launch_bounds__(256) void k_gemm_m(const u16* __restrict__ A0,
                                                const u16* __restrict__ A1,
                                                int astride,
                                                const u16* __restrict__ W,
                                                const float* __restrict__ bc,
                                                float* __restrict__ Gt) {
    __shared__ char At[128 * 128];
    __shared__ char Wt[128 * 128];
    int tid = threadIdx.x;
    int lane = tid & 63, w = tid >> 6;
    int n0 = blockIdx.x * 128, m0 = blockIdx.y * 128;
    int r = tid >> 1, h = tid & 1;      // staging: row r, half h

    f32x4 acc[4][4];
    #pragma unroll
    for (int i = 0; i < 4; ++i)
        #pragma unroll
        for (int j = 0; j < 4; ++j) acc[i][j] = (f32x4){0.f, 0.f, 0.f, 0.f};

    unsigned rsw = (unsigned)((r & 7) << 4);
    for (int kt = 0; kt < GK; kt += 64) {
        {
            int k0 = kt + h * 32;
            const u16* asrc = (k0 < 512) ? (A0 + (size_t)(m0 + r) * astride + k0)
                                         : (A1 + (size_t)(m0 + r) * astride + (k0 - 512));
            const u16* wsrc = W + (size_t)(n0 + r) * GK + k0;
            #pragma unroll
            for (int j = 0; j < 4; ++j) {
                uint4 va = *(const uint4*)(asrc + j * 8);
                *(uint4*)(At + r * 128 + (((unsigned)(h * 64 + j * 16)) ^ rsw)) = va;
                uint4 vw = *(const uint4*)(wsrc + j * 8);
                *(uint4*)(Wt + r * 128 + (((unsigned)(h * 64 + j * 16)) ^ rsw)) = vw;
            }
        }
        __syncthreads();
        #pragma unroll
        for (int sub = 0; sub < 2; ++sub) {
            bf16x8 af[4], bfr[4];
            int kbyte = sub * 64 + (lane >> 4) * 16;
            #pragma unroll
            for (int ni = 0; ni < 4; ++ni) {
                int rr = (w & 1) * 64 + ni * 16 + (lane & 15);
                af[ni] = *(const bf16x8*)(Wt + rr * 128 + ((unsigned)kbyte ^ ((unsigned)((rr & 7) << 4))));
            }
            #pragma unroll
            for (int mi = 0; mi < 4; ++mi) {
                int rr = (w >> 1) * 64 + mi * 16 + (lane & 15);
                bfr[mi] = *(const bf16x8*)(At + rr * 128 + ((unsigned)kbyte ^ ((unsigned)((rr & 7) << 4))));
            }
            #pragma unroll
            for (int mi = 0; mi < 4; ++mi)
                #pragma unroll
                for (int ni = 0; ni < 4; ++ni)
                    acc[mi][ni] = __builtin_amdgcn_mfma_f32_16x16x32_bf16(
                        af[ni], bfr[mi], acc[mi][ni], 0, 0, 0);
        }
        __syncthreads();
    }
    // epilogue: float4 (4 gates of one unit) -> Gt[slice16][t][b][uloc32][g]
    #pragma unroll
    for (int mi = 0; mi < 4; ++mi) {
        int mp = m0 + (w >> 1) * 64 + mi * 16 + (lane & 15);
        int t = mp >> 5, b = mp & 31;
        #pragma unroll
        for (int ni = 0; ni < 4; ++ni) {
            int npb = n0 + (w & 1) * 64 + ni * 16 + (lane >> 4) * 4;
            int unit = npb >> 2;
            float4 bv = *(const float4*)(bc + npb);
            f32x4 a = acc[mi][ni];
            float4 o = make_float4(a[0] + bv.x, a[1] + bv.y, a[2] + bv.z, a[3] + bv.w);
            *(float4*)(Gt + ((size_t)((unit >> 5) * NS + t)) * 4096 + b * 128 + (unit & 31) * 4) = o;
        }
    }
}

// ---------------------------------------------------------------------------
// Persistent MFMA LSTM, R9 exchange with HALF the participants.
// Grid = 32 WGs x 512 threads: wg&1 = dir, wg>>1 = slice (32 units).
// Wave w (0..7) owns units 4w..4w+3 (x4 gates) -> wfrag[16] resident.
// Per step (R9-verbatim protocol): stage h(t-1) 32KB -> swizzled LDS (one
// coalesced burst, 64B/thread); sync; 32 MFMA/wave; gates; scattered u16
// sc1 h-stores; vmcnt(0); sync; tid0 publishes step+1 to own 64B line
// (16 lines/dir); all lanes poll the 16 lines (4x cover) with relaxed
// agent loads + __all; G(t+1) prefetched between publish and poll.
// Monotonic lines zeroed per launch; publish precedes poll -> inductive
// progress (no deadlock), exactly as R9.
// ---------------------------------------------------------------------------
__global__ __launch_bounds__(512) void k_lstm_v(const float* __restrict__ Gt,
                                                const float* __restrict__ Whh,
                                                u16* __restrict__ hxb,
                                                int* __restrict__ cblk) {
    __shared__ char hlds[NB * NHD * 2];    // 32 KB bf16, swizzled
    int wg = blockIdx.x;
    int d = wg & 1;
    int slice = wg >> 1;            // 0..15
    int n0 = slice * UPW;
    int tid = threadIdx.x;
    int lane = tid & 63;
    int w = tid >> 6;               // wave 0..7
    int* lines  = cblk + d * 256;          // 16 lines x 16 ints (64B apart)
    int* myline = lines + slice * 16;
    int pollidx = (lane & 15) * 16;        // each lane polls one line (4x cover)
    u16* hxd = hxb + (size_t)d * NS * NB * NHD;
    const float* Gd = Gt + (size_t)d * GT_DIR + (size_t)slice * NS * 4096;

    // resident A fragments (Whh fp32 -> bf16); per-wave-unique rows
    bf16x8 wfrag[16];
    {
        int rloc = lane & 15;
        int usub = rloc >> 2, g = rloc & 3;
        int kb0 = lane >> 4;
        const float* wrow = Whh + ((size_t)d * NG + g * NHD + n0 + 4 * w + usub) * NHD;
        #pragma unroll
        for (int kk = 0; kk < 16; ++kk) {
            const float* p = wrow + kk * 32 + kb0 * 8;
            float4 x = *(const float4*)p;
            float4 y = *(const float4*)(p + 4);
            bf16x8 wf;
            wf[0] = (short)f2bf(x.x); wf[1] = (short)f2bf(x.y);
            wf[2] = (short)f2bf(x.z); wf[3] = (short)f2bf(x.w);
            wf[4] = (short)f2bf(y.x); wf[5] = (short)f2bf(y.y);
            wf[6] = (short)f2bf(y.z); wf[7] = (short)f2bf(y.w);
            wfrag[kk] = wf;
        }
    }
    int uloc  = 4 * w + (lane >> 4);       // unit within slice (C layout)
    int unitC = n0 + uloc;                 // global unit
    int bcol0 = lane & 15;                 // batch, tile 0
    int bcol1 = 16 + bcol0;                // batch, tile 1
    int kb    = lane >> 4;                 // B-fragment k-block
    int sRow = tid >> 4, c4 = tid & 15;    // staging: row 0..31, 64B chunk
    unsigned rsw = (unsigned)((sRow & 7) << 4);
    unsigned s0 = (unsigned)((bcol0 & 7) << 4);
    unsigned s1 = (unsigned)((bcol1 & 7) << 4);

    float c0 = 0.f, c1 = 0.f;
    // prologue: G prefetch for step 0
    int ttp = d ? (NS - 1) : 0;
    float4 Gv0 = *(const float4*)(Gd + (size_t)ttp * 4096 + bcol0 * 128 + uloc * 4);
    float4 Gv1 = *(const float4*)(Gd + (size_t)ttp * 4096 + bcol1 * 128 + uloc * 4);

    for (int step = 0; step < NS; ++step) {
        int tt = d ? (NS - 1 - step) : step;
        f32x4 acc0 = {0.f, 0.f, 0.f, 0.f};
        f32x4 acc1 = {0.f, 0.f, 0.f, 0.f};
        if (step) {
            int tprev = d ? tt + 1 : tt - 1;
            // stage hx_bf[tprev] (32KB) -> swizzled LDS: one coalesced burst
            const u16* srow = hxd + ((size_t)tprev * NB + sRow) * NHD + c4 * 32;
            char* dstrow = hlds + sRow * 1024;
            #pragma unroll
            for (int i = 0; i < 4; ++i) {
                uint4 v = *(const uint4*)(srow + i * 8);
                *(uint4*)(dstrow + (((unsigned)(c4 * 64 + i * 16)) ^ rsw)) = v;
            }
            __syncthreads();
            const char* b0base = hlds + bcol0 * 1024;
            const char* b1base = hlds + bcol1 * 1024;
            #pragma unroll
            for (int kk = 0; kk < 16; ++kk) {
                bf16x8 b0 = *(const bf16x8*)(b0base + (((unsigned)(kk * 64 + kb * 16)) ^ s0));
                bf16x8 b1 = *(const bf16x8*)(b1base + (((unsigned)(kk * 64 + kb * 16)) ^ s1));
                acc0 = __builtin_amdgcn_mfma_f32_16x16x32_bf16(wfrag[kk], b0, acc0, 0, 0, 0);
                acc1 = __builtin_amdgcn_mfma_f32_16x16x32_bf16(wfrag[kk], b1, acc1, 0, 0, 0);
            }
        }
        // gates (reg q = gate q: i,f,g,o) for (unitC, bcol0/1)
        {
            float ig = sigm(acc0[0] + Gv0.x);
            float fg = sigm(acc0[1] + Gv0.y);
            float gg = tanhfast(acc0[2] + Gv0.z);
            float og = sigm(acc0[3] + Gv0.w);
            c0 = fg * c0 + ig * gg;
            float hv = og * tanhfast(c0);
            __hip_atomic_store(hxd + ((size_t)tt * NB + bcol0) * NHD + unitC, f2bf(hv),
                               __ATOMIC_RELAXED, __HIP_MEMORY_SCOPE_AGENT);
        }
        {
            float ig = sigm(acc1[0] + Gv1.x);
            float fg = sigm(acc1[1] + Gv1.y);
            float gg = tanhfast(acc1[2] + Gv1.z);
            float og = sigm(acc1[3] + Gv1.w);
            c1 = fg * c1 + ig * gg;
            float hv = og * tanhfast(c1);
            __hip_atomic_store(hxd + ((size_t)tt * NB + bcol1) * NHD + unitC, f2bf(hv),
                               __ATOMIC_RELAXED, __HIP_MEMORY_SCOPE_AGENT);
        }
        if (step == NS - 1) break;          // last step: no exchange needed
        // all waves: stores drained, then WG-wide rendezvous
        asm volatile("s_waitcnt vmcnt(0)" ::: "memory");
        __syncthreads();           // all h stores done; all LDS reads done
        // publish: one relaxed store to own line (no RMW)
        if (tid == 0)
            __hip_atomic_store(myline, step + 1, __ATOMIC_RELAXED,
                               __HIP_MEMORY_SCOPE_AGENT);
        // prefetch next step's G (hides under the poll)
        {
            int ttn = d ? tt - 1 : tt + 1;
            Gv0 = *(const float4*)(Gd + (size_t)ttn * 4096 + bcol0 * 128 + uloc * 4);
            Gv1 = *(const float4*)(Gd + (size_t)ttn * 4096 + bcol1 * 128 + uloc * 4);
        }
        asm volatile("" ::: "memory");   // pin prefetch issue before poll
        // all waves poll the 16 lines in parallel
        {
            int target = step + 1;
            for (;;) {
                int v = __hip_atomic_load(lines + pollidx, __ATOMIC_RELAXED,
                                          __HIP_MEMORY_SCOPE_AGENT);
                if (__all(v >= target)) break;
                __builtin_amdgcn_s_sleep(1);
            }
        }
    }
}

// ---------------------------------------------------------------------------
// MLP stage 1: mid[512][1024] = relu(hrow @ W1^T + b1), rows from hx_bf
// ---------------------------------------------------------------------------
__global__ __launch_bounds__(256) void k_mlp1(const u16* __restrict__ hxb,
                                              const int* __restrict__ pidx,
                                              const float* __restrict__ W1,
                                              const float* __restrict__ b1,
                                              float* __restrict__ mid) {
    __shared__ float As[16][65];
    __shared__ float Ws[16][65];
    int tid = threadIdx.x;
    int tx = tid & 15, ty = tid >> 4;
    int n0 = blockIdx.x * 64, m0 = blockIdx.y * 64;
    int lr = tid >> 2;
    int lk = (tid & 3) * 4;
    int m = m0 + lr;
    int bb = m >> 4;
    int s = pidx[m];
    float acc[4][4] = {};
    for (int kt = 0; kt < GK; kt += 16) {
        int k0 = kt + lk;
        int half = k0 >> 9;
        ushort4 av4 = *(const ushort4*)(hxb + (((size_t)(half * NS + s)) * NB + bb) * NHD + (k0 & 511));
        float4 wv = *(const float4*)(W1 + (size_t)(n0 + lr) * GK + k0);
        As[lk + 0][lr] = bf2f(av4.x); As[lk + 1][lr] = bf2f(av4.y);
        As[lk + 2][lr] = bf2f(av4.z); As[lk + 3][lr] = bf2f(av4.w);
        Ws[lk + 0][lr] = wv.x; Ws[lk + 1][lr] = wv.y;
        Ws[lk + 2][lr] = wv.z; Ws[lk + 3][lr] = wv.w;
        __syncthreads();
        #pragma unroll
        for (int kk = 0; kk < 16; ++kk) {
            float a[4], wv2[4];
            #pragma unroll
            for (int i = 0; i < 4; ++i) a[i] = As[kk][ty * 4 + i];
            #pragma unroll
            for (int j = 0; j < 4; ++j) wv2[j] = Ws[kk][tx * 4 + j];
            #pragma unroll
            for (int i = 0; i < 4; ++i)
                #pragma unroll
                for (int j = 0; j < 4; ++j) acc[i][j] += a[i] * wv2[j];
        }
        __syncthreads();
    }
    #pragma unroll
    for (int j = 0; j < 4; ++j) {
        int n = n0 + tx * 4 + j;
        float bias = b1[n];
        #pragma unroll
        for (int i = 0; i < 4; ++i)
            mid[(size_t)(m0 + ty * 4 + i) * 1024 + n] = fmaxf(acc[i][j] + bias, 0.f);
    }
}

// ---------------------------------------------------------------------------
// MLP stage 2: out[b, s] = mid @ W2^T + b2 + pemb[p], scattered to d_out.
// ---------------------------------------------------------------------------
__global__ __launch_bounds__(256) void k_mlp2(const float* __restrict__ mid,
                                              const int* __restrict__ pidx,
                                              const float* __restrict__ W2,
                                              const float* __restrict__ b2,
                                              const float* __restrict__ pemb,
                                              float* __restrict__ out) {
    __shared__ float As[16][65];
    __shared__ float Ws[16][65];
    int tid = threadIdx.x;
    int tx = tid & 15, ty = tid >> 4;
    int n0 = blockIdx.x * 64, m0 = blockIdx.y * 64;
    int lr = tid >> 2;
    int lk = (tid & 3) * 4;
    float acc[4][4] = {};
    for (int kt = 0; kt < GK; kt += 16) {
        float4 av = *(const float4*)(mid + (size_t)(m0 + lr) * GK + kt + lk);
        float4 wv = *(const float4*)(W2 + (size_t)(n0 + lr) * GK + kt + lk);
        As[lk + 0][lr] = av.x; As[lk + 1][lr] = av.y;
        As[lk + 2][lr] = av.z; As[lk + 3][lr] = av.w;
        Ws[lk + 0][lr] = wv.x; Ws[lk + 1][lr] = wv.y;
        Ws[lk + 2][lr] = wv.z; Ws[lk + 3][lr] = wv.w;
        __syncthreads();
        #pragma unroll
        for (int kk = 0; kk < 16; ++kk) {
            float a[4], wv2[4];
            #pragma unroll
            for (int i = 0; i < 4; ++i) a[i] = As[kk][ty * 4 + i];
            #pragma unroll
            for (int j = 0; j < 4; ++j) wv2[j] = Ws[kk][tx * 4 + j];
            #pragma unroll
            for (int i = 0; i < 4; ++i)
                #pragma unroll
                for (int j = 0; j < 4; ++j) acc[i][j] += a[i] * wv2[j];
        }
        __syncthreads();
    }
    #pragma unroll
    for (int i = 0; i < 4; ++i) {
        int m = m0 + ty * 4 + i;
        int bb = m >> 4, p = m & 15;
        int s = pidx[m];
        float* orow = out + ((size_t)(bb * NS + s)) * NE;
        const float* prow = pemb + (size_t)p * NE;
        #pragma unroll
        for (int j = 0; j < 4; ++j) {
            int n = n0 + tx * 4 + j;
            orow[n] = acc[i][j] + b2[n] + prow[n];
        }
    }
}

// ---------------------------------------------------------------------------
extern "C" void kernel_launch(void* const* d_in, const int* in_sizes, int n_in,
                              void* d_out, int out_size, void* d_ws, size_t ws_size,
                              hipStream_t stream) {
    const float* emb  = (const float*)d_in[0];
    const float* ctx  = (const float*)d_in[1];
    const float* pemb = (const float*)d_in[2];
    const float* Wih0 = (const float*)d_in[3];
    const float* Whh0 = (const float*)d_in[4];
    const float* bih0 = (const float*)d_in[5];
    const float* bhh0 = (const float*)d_in[6];
    const float* Wih1 = (const float*)d_in[7];
    const float* Whh1 = (const float*)d_in[8];
    const float* bih1 = (const float*)d_in[9];
    const float* bhh1 = (const float*)d_in[10];
    const float* W1   = (const float*)d_in[11];
    const float* b1   = (const float*)d_in[12];
    const float* W2   = (const float*)d_in[13];
    const float* b2   = (const float*)d_in[14];
    const int* ids    = (const int*)d_in[15];
    const int* pidx   = (const int*)d_in[16];
    float* out = (float*)d_out;

    // Workspace layout (bytes):
    //   Gt:    [2][16][256][4096] f32 = 134217728
    //   allb:  [256][32][1024] bf16   =  16777216
    //   hx_bf: [2][256][32][512] bf16 =  16777216
    //   Wbf:   [2][2048][1024] bf16   =   8388608
    //   biasC: [2][2048] f32          =     16384
    //   mid:   [512][1024] f32        =   2097152
    //   ctr:   1024 ints (2 layers x 2 dirs x 16 lines x 16 ints)
    char* ws = (char*)d_ws;
    float* Gt    = (float*)ws;
    u16*   allb  = (u16*)(ws + 134217728u);
    u16*   hx    = (u16*)(ws + 150994944u);
    u16*   Wbf   = (u16*)(ws + 167772160u);
    float* biasC = (float*)(ws + 176160768u);
    float* mid   = (float*)(ws + 176177152u);
    int*   ctr   = (int*)(ws + 178274304u);

    k_zero<<<dim3(4), dim3(256), 0, stream>>>(ctr);
    k_allb<<<dim3(NBS), dim3(256), 0, stream>>>(emb, ctx, pemb, ids, pidx, allb);

    // Layer 0
    k_wcvt<<<dim3(2 * NG), dim3(256), 0, stream>>>(Wih0, bih0, bhh0, Wbf, biasC);
    for (int d = 0; d < 2; ++d)
        k_gemm_m<<<dim3(NG / 128, NBS / 128), dim3(256), 0, stream>>>(
            allb, allb + 512, 1024, Wbf + (size_t)d * NG * GK, biasC + d * NG,
            Gt + (size_t)d * GT_DIR);
    k_lstm_v<<<dim3(2 * NWGD), dim3(512), 0, stream>>>(Gt, Whh0, hx, ctr);

    k_raw<<<dim3(NBS), dim3(256), 0, stream>>>(emb, ids, out);

    // Layer 1 (A = hx_bf, dir halves)
    k_wcvt<<<dim3(2 * NG), dim3(256), 0, stream>>>(Wih1, bih1, bhh1, Wbf, biasC);
    for (int d = 0; d < 2; ++d)
        k_gemm_m<<<dim3(NG / 128, NBS / 128), dim3(256), 0, stream>>>(
            hx, hx + (size_t)NS * NB * NHD, 512, Wbf + (size_t)d * NG * GK,
            biasC + d * NG, Gt + (size_t)d * GT_DIR);
    k_lstm_v<<<dim3(2 * NWGD), dim3(512), 0, stream>>>(Gt, Whh1, hx, ctr + 512);

    // MLP head at prompt rows
    k_mlp1<<<dim3(16, 8), dim3(256), 0, stream>>>(hx, pidx, W1, b1, mid);
    k_mlp2<<<dim3(16, 8), dim3(256), 0, stream>>>(mid, pidx, W2, b2, pemb, out);
}

// Round 14
// 2199.976 us; speedup vs baseline: 1.6482x; 1.0952x over previous
//
#include <hip/hip_runtime.h>
#include <hip/hip_bf16.h>
#include <math.h>

// Problem constants
constexpr int NB  = 32;      // batch
constexpr int NS  = 256;     // seq len
constexpr int NE  = 1024;    // embed dim
constexpr int NH  = 1024;    // LSTM output dim (2*NHD)
constexpr int NHD = 512;     // per-direction hidden
constexpr int NG  = 2048;    // 4*NHD gates
constexpr int NP  = 16;      // prompt positions
constexpr int NBS = NB * NS; // 8192 rows
constexpr int GK  = 1024;    // GEMM K (= NE = NH)

// Persistent LSTM decomposition: UPW=16 units/WG, 32 WGs/dir, 64 total
constexpr int UPW  = 16;
constexpr int NWGD = NHD / UPW;  // 32 WGs per direction
// Gt layout: [d][slice 32][t 256][b 32][uloc 16][gate 4] fp32
constexpr size_t GT_DIR = (size_t)NWGD * 256 * 2048;   // 16.7M elems/dir

typedef __attribute__((ext_vector_type(8))) short bf16x8;
typedef __attribute__((ext_vector_type(4))) float f32x4;
typedef unsigned short u16;
typedef unsigned long long u64;

__device__ __forceinline__ float sigm(float x) {
    return __fdividef(1.0f, 1.0f + __expf(-x));
}
__device__ __forceinline__ float tanhfast(float x) {
    float t = __expf(2.0f * x);
    return 1.0f - __fdividef(2.0f, t + 1.0f);
}
__device__ __forceinline__ u16 f2bf(float f) {
    union { float f; unsigned u; } v; v.f = f;
    unsigned r = v.u + 0x7FFF + ((v.u >> 16) & 1);   // RNE
    return (u16)(r >> 16);
}
__device__ __forceinline__ float bf2f(u16 b) {
    return __uint_as_float((unsigned)b << 16);
}

// ---------------------------------------------------------------------------
__global__ void k_zero(int* p) { p[blockIdx.x * 256 + threadIdx.x] = 0; }

// ---------------------------------------------------------------------------
// allb_bf[s][b][1024] (bf16) = emb[id]+ctx[id], prompt_emb at prompt slots
// ---------------------------------------------------------------------------
__global__ void k_allb(const float* __restrict__ emb, const float* __restrict__ ctx,
                       const float* __restrict__ pemb, const int* __restrict__ ids,
                       const int* __restrict__ pidx, u16* __restrict__ allb) {
    int r = blockIdx.x;            // r = b*NS + s
    int b = r >> 8, s = r & 255;
    __shared__ int ppos;
    if (threadIdx.x == 0) {
        int t = -1;
        #pragma unroll
        for (int p = 0; p < NP; ++p)
            if (pidx[b * NP + p] == s) t = p;
        ppos = t;
    }
    __syncthreads();
    int e = threadIdx.x;
    float4 v;
    if (ppos >= 0) {
        v = ((const float4*)(pemb + (size_t)ppos * NE))[e];
    } else {
        int id = ids[r];
        float4 a = ((const float4*)(emb + (size_t)id * NE))[e];
        float4 c = ((const float4*)(ctx + (size_t)id * NE))[e];
        v = make_float4(a.x + c.x, a.y + c.y, a.z + c.z, a.w + c.w);
    }
    ushort4 o;
    o.x = f2bf(v.x); o.y = f2bf(v.y); o.z = f2bf(v.z); o.w = f2bf(v.w);
    *(ushort4*)(allb + ((size_t)(s * NB + b)) * NE + e * 4) = o;
}

// ---------------------------------------------------------------------------
// Wih ([2][2048][1024] fp32, gate-major rows) -> Wbf (bf16, UNIT-MAJOR rows:
// n' = unit*4+gate) + combined bias in same order.
// ---------------------------------------------------------------------------
__global__ void k_wcvt(const float* __restrict__ Wih, const float* __restrict__ bih,
                       const float* __restrict__ bhh, u16* __restrict__ Wbf,
                       float* __restrict__ biasC) {
    int blk = blockIdx.x;               // [2][2048]
    int d = blk >> 11, np = blk & 2047;
    int rw = (np & 3) * 512 + (np >> 2);
    const float* src = Wih + ((size_t)d * NG + rw) * GK;
    u16* dst = Wbf + ((size_t)d * NG + np) * GK;
    int t = threadIdx.x;
    float4 v = ((const float4*)src)[t];
    ushort4 o;
    o.x = f2bf(v.x); o.y = f2bf(v.y); o.z = f2bf(v.z); o.w = f2bf(v.w);
    ((ushort4*)dst)[t] = o;
    if (t == 0)
        biasC[d * NG + np] = bih[d * NG + rw] + bhh[d * NG + rw];
}

// ---------------------------------------------------------------------------
// MEGA KERNEL: fused {persistent LSTM consumers | GEMM producers | raw copy}.
// Grid (mega-0) = 64 lstm + 2048 gemm + 8192 raw = 10304; mega-1 = 2112.
//  - WGs 0..63: R9-verbatim persistent lstm (UPW=16; store-publish h-lines;
//    plain cached staging) + per-t-group Gt-availability poll before each
//    G-prefetch (counter = 16 n-blocks done).
//  - WGs 64..2111: 128x128 bf16 MFMA GEMM blocks producing Gt. T-ORDERED:
//    d0 blocks compute t ascending, d1 descending, interleaved, so each
//    direction's earliest-needed groups are produced first. Gt written via
//    sc1 u64 atomic stores (cross-XCD visible w/o dispatch boundary);
//    vmcnt(0) + sync + one fetch_add publishes gcnt[d][tgroup].
//  - WGs 2112+: raw-copy out[r] = emb[ids[r]] (no sync; mega-0 only).
// Acyclic waits (lstm->gemm counters only; gemm/raw never wait), lstm WGs
// first in dispatch order (resident), finite producers retire -> no
// deadlock. Staleness: within-dispatch consumers first-touch Gt/hx lines
// only post-poll; layer-1 lstm writes hx1 (reused allb) so mega-1's gemm
// reads of hx0 can't alias lstm-1's staging lines.
// ctrL layout (ints): [0..1023] h-lines (d*512 + slice*16);
//                     [1024..3071] gcnt ((d*64+by)*16).
// ---------------------------------------------------------------------------
__global__ __launch_bounds__(256) void k_mega(
        const u16* __restrict__ A0, const u16* __restrict__ A1, int astride,
        const u16* __restrict__ Wbf, const float* __restrict__ biasC,
        float* __restrict__ Gt, const float* __restrict__ Whh,
        u16* __restrict__ hxb, int* __restrict__ ctrL,
        const float* __restrict__ emb, const int* __restrict__ ids,
        float* __restrict__ rawout) {
    __shared__ char smem[32768];
    int wg = blockIdx.x;
    int tid = threadIdx.x;

    // ================= raw-copy WGs (mega-0 only) =================
    if (wg >= 2112) {
        int r = wg - 2112;
        int id = ids[r];
        ((float4*)(rawout + (size_t)r * NE))[tid] =
            ((const float4*)(emb + (size_t)id * NE))[tid];
        return;
    }

    // ================= GEMM producer WGs =================
    if (wg >= 64) {
        char* At = smem;
        char* Wt = smem + 16384;
        int gb  = wg - 64;
        int ord = gb >> 5;
        int rem = gb & 31;
        int d   = rem & 1;
        int bx  = rem >> 1;
        int by  = d ? (63 - ord) : ord;     // t-order per direction
        const u16* W = Wbf + (size_t)d * NG * GK;
        const float* bc = biasC + d * NG;
        float* Gd = Gt + (size_t)d * GT_DIR;
        int lane = tid & 63, w = tid >> 6;
        int n0 = bx * 128, m0 = by * 128;
        int r = tid >> 1, h = tid & 1;

        f32x4 acc[4][4];
        #pragma unroll
        for (int i = 0; i < 4; ++i)
            #pragma unroll
            for (int j = 0; j < 4; ++j) acc[i][j] = (f32x4){0.f, 0.f, 0.f, 0.f};

        unsigned rsw = (unsigned)((r & 7) << 4);
        for (int kt = 0; kt < GK; kt += 64) {
            {
                int k0 = kt + h * 32;
                const u16* asrc = (k0 < 512) ? (A0 + (size_t)(m0 + r) * astride + k0)
                                             : (A1 + (size_t)(m0 + r) * astride + (k0 - 512));
                const u16* wsrc = W + (size_t)(n0 + r) * GK + k0;
                #pragma unroll
                for (int j = 0; j < 4; ++j) {
                    uint4 va = *(const uint4*)(asrc + j * 8);
                    *(uint4*)(At + r * 128 + (((unsigned)(h * 64 + j * 16)) ^ rsw)) = va;
                    uint4 vw = *(const uint4*)(wsrc + j * 8);
                    *(uint4*)(Wt + r * 128 + (((unsigned)(h * 64 + j * 16)) ^ rsw)) = vw;
                }
            }
            __syncthreads();
            #pragma unroll
            for (int sub = 0; sub < 2; ++sub) {
                bf16x8 af[4], bfr[4];
                int kbyte = sub * 64 + (lane >> 4) * 16;
                #pragma unroll
                for (int ni = 0; ni < 4; ++ni) {
                    int rr = (w & 1) * 64 + ni * 16 + (lane & 15);
                    af[ni] = *(const bf16x8*)(Wt + rr * 128 + ((unsigned)kbyte ^ ((unsigned)((rr & 7) << 4))));
                }
                #pragma unroll
                for (int mi = 0; mi < 4; ++mi) {
                    int rr = (w >> 1) * 64 + mi * 16 + (lane & 15);
                    bfr[mi] = *(const bf16x8*)(At + rr * 128 + ((unsigned)kbyte ^ ((unsigned)((rr & 7) << 4))));
                }
                #pragma unroll
                for (int mi = 0; mi < 4; ++mi)
                    #pragma unroll
                    for (int ni = 0; ni < 4; ++ni)
                        acc[mi][ni] = __builtin_amdgcn_mfma_f32_16x16x32_bf16(
                            af[ni], bfr[mi], acc[mi][ni], 0, 0, 0);
            }
            __syncthreads();
        }
        // epilogue: Gt[slice][t][b][uloc][g] via sc1 u64 atomic stores
        #pragma unroll
        for (int mi = 0; mi < 4; ++mi) {
            int mp = m0 + (w >> 1) * 64 + mi * 16 + (lane & 15);
            int t = mp >> 5, b = mp & 31;
            #pragma unroll
            for (int ni = 0; ni < 4; ++ni) {
                int npb = n0 + (w & 1) * 64 + ni * 16 + (lane >> 4) * 4;
                int unit = npb >> 2;
                float4 bv = *(const float4*)(bc + npb);
                f32x4 a = acc[mi][ni];
                union { float4 f; u64 q[2]; } cv;
                cv.f = make_float4(a[0] + bv.x, a[1] + bv.y, a[2] + bv.z, a[3] + bv.w);
                float* p = Gd + ((size_t)((unit >> 4) * NS + t)) * 2048 + b * 64 + (unit & 15) * 4;
                __hip_atomic_store((u64*)p,     cv.q[0], __ATOMIC_RELAXED, __HIP_MEMORY_SCOPE_AGENT);
                __hip_atomic_store((u64*)p + 1, cv.q[1], __ATOMIC_RELAXED, __HIP_MEMORY_SCOPE_AGENT);
            }
        }
        asm volatile("s_waitcnt vmcnt(0)" ::: "memory");
        __syncthreads();
        if (tid == 0)
            __hip_atomic_fetch_add(ctrL + 1024 + (d * 64 + by) * 16, 1,
                                   __ATOMIC_RELAXED, __HIP_MEMORY_SCOPE_AGENT);
        return;
    }

    // ================= persistent lstm WGs (R9-verbatim + Gt poll) =========
    char* hlds = smem;              // 32 KB bf16 h-tile, swizzled
    int d = wg & 1;
    int slice = wg >> 1;            // 0..31
    int n0 = slice * UPW;
    int lane = tid & 63;
    int w = tid >> 6;               // wave 0..3
    int* lines  = ctrL + d * 512;          // 32 lines x 16 ints
    int* myline = lines + slice * 16;
    int* gcnt   = ctrL + 1024;
    int pollidx = (lane & 31) * 16;
    u16* hxd = hxb + (size_t)d * NS * NB * NHD;
    const float* Gd = Gt + (size_t)d * GT_DIR + (size_t)slice * NS * 2048;

    // resident A fragments (Whh fp32 -> bf16); per-wave-unique rows
    bf16x8 wfrag[16];
    {
        int rloc = lane & 15;
        int usub = rloc >> 2, g = rloc & 3;
        int kb0 = lane >> 4;
        const float* wrow = Whh + ((size_t)d * NG + g * NHD + n0 + 4 * w + usub) * NHD;
        #pragma unroll
        for (int kk = 0; kk < 16; ++kk) {
            const float* p = wrow + kk * 32 + kb0 * 8;
            float4 x = *(const float4*)p;
            float4 y = *(const float4*)(p + 4);
            bf16x8 wf;
            wf[0] = (short)f2bf(x.x); wf[1] = (short)f2bf(x.y);
            wf[2] = (short)f2bf(x.z); wf[3] = (short)f2bf(x.w);
            wf[4] = (short)f2bf(y.x); wf[5] = (short)f2bf(y.y);
            wf[6] = (short)f2bf(y.z); wf[7] = (short)f2bf(y.w);
            wfrag[kk] = wf;
        }
    }
    int uloc  = 4 * w + (lane >> 4);
    int unitC = n0 + uloc;
    int bcol0 = lane & 15;
    int bcol1 = 16 + bcol0;
    int kb    = lane >> 4;
    int c8 = tid & 7, bRow = tid >> 3;
    unsigned rsw = (unsigned)((bRow & 7) << 4);
    unsigned s0 = (unsigned)((bcol0 & 7) << 4);
    unsigned s1 = (unsigned)((bcol1 & 7) << 4);

    float c0 = 0.f, c1 = 0.f;
    int gReady = -1;
    // prologue: wait for step-0's Gt group, then prefetch G
    int ttp = d ? (NS - 1) : 0;
    {
        int g0 = ttp >> 2;
        int* gl = gcnt + (d * 64 + g0) * 16;
        while (__hip_atomic_load(gl, __ATOMIC_RELAXED, __HIP_MEMORY_SCOPE_AGENT) < 16)
            __builtin_amdgcn_s_sleep(1);
        gReady = g0;
    }
    float4 Gv0 = *(const float4*)(Gd + (size_t)ttp * 2048 + bcol0 * 64 + uloc * 4);
    float4 Gv1 = *(const float4*)(Gd + (size_t)ttp * 2048 + bcol1 * 64 + uloc * 4);

    for (int step = 0; step < NS; ++step) {
        int tt = d ? (NS - 1 - step) : step;
        f32x4 acc0 = {0.f, 0.f, 0.f, 0.f};
        f32x4 acc1 = {0.f, 0.f, 0.f, 0.f};
        if (step) {
            int tprev = d ? tt + 1 : tt - 1;
            const u16* srow = hxd + ((size_t)tprev * NB + bRow) * NHD;
            char* dstrow = hlds + bRow * 1024;
            #pragma unroll
            for (int i = 0; i < 8; ++i) {
                uint4 v = *(const uint4*)(srow + c8 * 64 + i * 8);
                *(uint4*)(dstrow + (((unsigned)(c8 * 128 + i * 16)) ^ rsw)) = v;
            }
            __syncthreads();
            const char* b0base = hlds + bcol0 * 1024;
            const char* b1base = hlds + bcol1 * 1024;
            #pragma unroll
            for (int kk = 0; kk < 16; ++kk) {
                bf16x8 b0 = *(const bf16x8*)(b0base + (((unsigned)(kk * 64 + kb * 16)) ^ s0));
                bf16x8 b1 = *(const bf16x8*)(b1base + (((unsigned)(kk * 64 + kb * 16)) ^ s1));
                acc0 = __builtin_amdgcn_mfma_f32_16x16x32_bf16(wfrag[kk], b0, acc0, 0, 0, 0);
                acc1 = __builtin_amdgcn_mfma_f32_16x16x32_bf16(wfrag[kk], b1, acc1, 0, 0, 0);
            }
        }
        {
            float ig = sigm(acc0[0] + Gv0.x);
            float fg = sigm(acc0[1] + Gv0.y);
            float gg = tanhfast(acc0[2] + Gv0.z);
            float og = sigm(acc0[3] + Gv0.w);
            c0 = fg * c0 + ig * gg;
            float hv = og * tanhfast(c0);
            __hip_atomic_store(hxd + ((size_t)tt * NB + bcol0) * NHD + unitC, f2bf(hv),
                               __ATOMIC_RELAXED, __HIP_MEMORY_SCOPE_AGENT);
        }
        {
            float ig = sigm(acc1[0] + Gv1.x);
            float fg = sigm(acc1[1] + Gv1.y);
            float gg = tanhfast(acc1[2] + Gv1.z);
            float og = sigm(acc1[3] + Gv1.w);
            c1 = fg * c1 + ig * gg;
            float hv = og * tanhfast(c1);
            __hip_atomic_store(hxd + ((size_t)tt * NB + bcol1) * NHD + unitC, f2bf(hv),
                               __ATOMIC_RELAXED, __HIP_MEMORY_SCOPE_AGENT);
        }
        if (step == NS - 1) break;
        asm volatile("s_waitcnt vmcnt(0)" ::: "memory");
        __syncthreads();
        if (tid == 0)
            __hip_atomic_store(myline, step + 1, __ATOMIC_RELAXED,
                               __HIP_MEMORY_SCOPE_AGENT);
        // Gt-group gate for t+1 (counter full after warmup: one cheap load)
        {
            int ttn = d ? tt - 1 : tt + 1;
            int g = ttn >> 2;
            if (g != gReady) {
                int* gl = gcnt + (d * 64 + g) * 16;
                while (__hip_atomic_load(gl, __ATOMIC_RELAXED, __HIP_MEMORY_SCOPE_AGENT) < 16)
                    __builtin_amdgcn_s_sleep(1);
                gReady = g;
            }
            Gv0 = *(const float4*)(Gd + (size_t)ttn * 2048 + bcol0 * 64 + uloc * 4);
            Gv1 = *(const float4*)(Gd + (size_t)ttn * 2048 + bcol1 * 64 + uloc * 4);
        }
        asm volatile("" ::: "memory");
        {
            int target = step + 1;
            for (;;) {
                int v = __hip_atomic_load(lines + pollidx, __ATOMIC_RELAXED,
                                          __HIP_MEMORY_SCOPE_AGENT);
                if (__all(v >= target)) break;
                __builtin_amdgcn_s_sleep(1);
            }
        }
    }
}

// ---------------------------------------------------------------------------
// MLP stage 1: mid[512][1024] = relu(hrow @ W1^T + b1), rows from hx_bf
// ---------------------------------------------------------------------------
__global__ __launch_bounds__(256) void k_mlp1(const u16* __restrict__ hxb,
                                              const int* __restrict__ pidx,
                                              const float* __restrict__ W1,
                                              const float* __restrict__ b1,
                                              float* __restrict__ mid) {
    __shared__ float As[16][65];
    __shared__ float Ws[16][65];
    int tid = threadIdx.x;
    int tx = tid & 15, ty = tid >> 4;
    int n0 = blockIdx.x * 64, m0 = blockIdx.y * 64;
    int lr = tid >> 2;
    int lk = (tid & 3) * 4;
    int m = m0 + lr;
    int bb = m >> 4;
    int s = pidx[m];
    float acc[4][4] = {};
    for (int kt = 0; kt < GK; kt += 16) {
        int k0 = kt + lk;
        int half = k0 >> 9;
        ushort4 av4 = *(const ushort4*)(hxb + (((size_t)(half * NS + s)) * NB + bb) * NHD + (k0 & 511));
        float4 wv = *(const float4*)(W1 + (size_t)(n0 + lr) * GK + k0);
        As[lk + 0][lr] = bf2f(av4.x); As[lk + 1][lr] = bf2f(av4.y);
        As[lk + 2][lr] = bf2f(av4.z); As[lk + 3][lr] = bf2f(av4.w);
        Ws[lk + 0][lr] = wv.x; Ws[lk + 1][lr] = wv.y;
        Ws[lk + 2][lr] = wv.z; Ws[lk + 3][lr] = wv.w;
        __syncthreads();
        #pragma unroll
        for (int kk = 0; kk < 16; ++kk) {
            float a[4], wv2[4];
            #pragma unroll
            for (int i = 0; i < 4; ++i) a[i] = As[kk][ty * 4 + i];
            #pragma unroll
            for (int j = 0; j < 4; ++j) wv2[j] = Ws[kk][tx * 4 + j];
            #pragma unroll
            for (int i = 0; i < 4; ++i)
                #pragma unroll
                for (int j = 0; j < 4; ++j) acc[i][j] += a[i] * wv2[j];
        }
        __syncthreads();
    }
    #pragma unroll
    for (int j = 0; j < 4; ++j) {
        int n = n0 + tx * 4 + j;
        float bias = b1[n];
        #pragma unroll
        for (int i = 0; i < 4; ++i)
            mid[(size_t)(m0 + ty * 4 + i) * 1024 + n] = fmaxf(acc[i][j] + bias, 0.f);
    }
}

// ---------------------------------------------------------------------------
// MLP stage 2: out[b, s] = mid @ W2^T + b2 + pemb[p], scattered to d_out.
// ---------------------------------------------------------------------------
__global__ __launch_bounds__(256) void k_mlp2(const float* __restrict__ mid,
                                              const int* __restrict__ pidx,
                                              const float* __restrict__ W2,
                                              const float* __restrict__ b2,
                                              const float* __restrict__ pemb,
                                              float* __restrict__ out) {
    __shared__ float As[16][65];
    __shared__ float Ws[16][65];
    int tid = threadIdx.x;
    int tx = tid & 15, ty = tid >> 4;
    int n0 = blockIdx.x * 64, m0 = blockIdx.y * 64;
    int lr = tid >> 2;
    int lk = (tid & 3) * 4;
    float acc[4][4] = {};
    for (int kt = 0; kt < GK; kt += 16) {
        float4 av = *(const float4*)(mid + (size_t)(m0 + lr) * GK + kt + lk);
        float4 wv = *(const float4*)(W2 + (size_t)(n0 + lr) * GK + kt + lk);
        As[lk + 0][lr] = av.x; As[lk + 1][lr] = av.y;
        As[lk + 2][lr] = av.z; As[lk + 3][lr] = av.w;
        Ws[lk + 0][lr] = wv.x; Ws[lk + 1][lr] = wv.y;
        Ws[lk + 2][lr] = wv.z; Ws[lk + 3][lr] = wv.w;
        __syncthreads();
        #pragma unroll
        for (int kk = 0; kk < 16; ++kk) {
            float a[4], wv2[4];
            #pragma unroll
            for (int i = 0; i < 4; ++i) a[i] = As[kk][ty * 4 + i];
            #pragma unroll
            for (int j = 0; j < 4; ++j) wv2[j] = Ws[kk][tx * 4 + j];
            #pragma unroll
            for (int i = 0; i < 4; ++i)
                #pragma unroll
                for (int j = 0; j < 4; ++j) acc[i][j] += a[i] * wv2[j];
        }
        __syncthreads();
    }
    #pragma unroll
    for (int i = 0; i < 4; ++i) {
        int m = m0 + ty * 4 + i;
        int bb = m >> 4, p = m & 15;
        int s = pidx[m];
        float* orow = out + ((size_t)(bb * NS + s)) * NE;
        const float* prow = pemb + (size_t)p * NE;
        #pragma unroll
        for (int j = 0; j < 4; ++j) {
            int n = n0 + tx * 4 + j;
            orow[n] = acc[i][j] + b2[n] + prow[n];
        }
    }
}

// ---------------------------------------------------------------------------
extern "C" void kernel_launch(void* const* d_in, const int* in_sizes, int n_in,
                              void* d_out, int out_size, void* d_ws, size_t ws_size,
                              hipStream_t stream) {
    const float* emb  = (const float*)d_in[0];
    const float* ctx  = (const float*)d_in[1];
    const float* pemb = (const float*)d_in[2];
    const float* Wih0 = (const float*)d_in[3];
    const float* Whh0 = (const float*)d_in[4];
    const float* bih0 = (const float*)d_in[5];
    const float* bhh0 = (const float*)d_in[6];
    const float* Wih1 = (const float*)d_in[7];
    const float* Whh1 = (const float*)d_in[8];
    const float* bih1 = (const float*)d_in[9];
    const float* bhh1 = (const float*)d_in[10];
    const float* W1   = (const float*)d_in[11];
    const float* b1   = (const float*)d_in[12];
    const float* W2   = (const float*)d_in[13];
    const float* b2   = (const float*)d_in[14];
    const int* ids    = (const int*)d_in[15];
    const int* pidx   = (const int*)d_in[16];
    float* out = (float*)d_out;

    // Workspace layout (bytes):
    //   Gt:    [2][32][256][2048] f32 = 134217728
    //   allb:  [256][32][1024] bf16   =  16777216  (reused as hx1 in layer 1)
    //   hx0:   [2][256][32][512] bf16 =  16777216
    //   Wbf:   [2][2048][1024] bf16   =   8388608
    //   biasC: [2][2048] f32          =     16384
    //   mid:   [512][1024] f32        =   2097152
    //   ctr:   6144 ints (2 layers x 3072: 1024 h-lines + 2048 gcnt)
    char* ws = (char*)d_ws;
    float* Gt    = (float*)ws;
    u16*   allb  = (u16*)(ws + 134217728u);
    u16*   hx0   = (u16*)(ws + 150994944u);
    u16*   Wbf   = (u16*)(ws + 167772160u);
    float* biasC = (float*)(ws + 176160768u);
    float* mid   = (float*)(ws + 176177152u);
    int*   ctr   = (int*)(ws + 178274304u);
    u16*   hx1   = allb;   // allb is dead after mega-0's GEMMs

    k_zero<<<dim3(24), dim3(256), 0, stream>>>(ctr);
    k_allb<<<dim3(NBS), dim3(256), 0, stream>>>(emb, ctx, pemb, ids, pidx, allb);

    // Layer 0: fused {GEMM producers + persistent lstm + raw copy}
    k_wcvt<<<dim3(2 * NG), dim3(256), 0, stream>>>(Wih0, bih0, bhh0, Wbf, biasC);
    k_mega<<<dim3(64 + 2048 + NBS), dim3(256), 0, stream>>>(
        allb, allb + 512, 1024, Wbf, biasC, Gt, Whh0, hx0, ctr,
        emb, ids, out);

    // Layer 1: fused {GEMM (reads hx0) + persistent lstm (writes hx1)}
    k_wcvt<<<dim3(2 * NG), dim3(256), 0, stream>>>(Wih1, bih1, bhh1, Wbf, biasC);
    k_mega<<<dim3(64 + 2048), dim3(256), 0, stream>>>(
        hx0, hx0 + (size_t)NS * NB * NHD, 512, Wbf, biasC, Gt, Whh1, hx1,
        ctr + 3072, emb, ids, out);

    // MLP head at prompt rows
    k_mlp1<<<dim3(16, 8), dim3(256), 0, stream>>>(hx1, pidx, W1, b1, mid);
    k_mlp2<<<dim3(16, 8), dim3(256), 0, stream>>>(mid, pidx, W2, b2, pemb, out);
}